// Round 7
// baseline (183.792 us; speedup 1.0000x reference)
//
#include <hip/hip_runtime.h>
#include <hip/hip_cooperative_groups.h>
#include <math.h>

namespace cg = cooperative_groups;

#define BB 1024
#define LL 256
#define VV 50000
#define EE 300
#define AA 30
#define WORD_THRES 0.2f
#define COS_EPS_F 1e-8f
#define NEG_INF_F -1e9f
#define RECHECK_DELTA 2e-4f
#define CGRID 256
#define NTILES 782            // ceil(50000 / 64)

typedef __attribute__((ext_vector_type(8))) short bf16x8;
typedef __attribute__((ext_vector_type(4))) float f32x4;

#define MFMA16(a, b, c) __builtin_amdgcn_mfma_f32_16x16x32_bf16((a), (b), (c), 0, 0, 0)

// async global -> LDS DMA, 16 B per lane, no VGPR destination.
__device__ __forceinline__ void gld_lds16(const float* g, float* l) {
    typedef const __attribute__((address_space(1))) void* gas_p;
    typedef __attribute__((address_space(3))) void* las_p;
    __builtin_amdgcn_global_load_lds((gas_p)g, (las_p)l, 16, 0, 0);
}

// fp32 -> bf16 truncation split: x = hi + lo with |x - hi - lo| <~ 2^-17 |x|.
__device__ __forceinline__ unsigned pack_hi(float a, float b) {
    return (__float_as_uint(a) >> 16) | (__float_as_uint(b) & 0xFFFF0000u);
}
__device__ __forceinline__ float hi_part(float a) {
    return __uint_as_float(__float_as_uint(a) & 0xFFFF0000u);
}
__device__ __forceinline__ void cvt_hilo(const float4 f0, const float4 f1,
                                         uint4& uh, uint4& ul) {
    uh.x = pack_hi(f0.x, f0.y);
    uh.y = pack_hi(f0.z, f0.w);
    uh.z = pack_hi(f1.x, f1.y);
    uh.w = pack_hi(f1.z, f1.w);
    const float l0 = f0.x - hi_part(f0.x), l1 = f0.y - hi_part(f0.y);
    const float l2 = f0.z - hi_part(f0.z), l3 = f0.w - hi_part(f0.w);
    const float l4 = f1.x - hi_part(f1.x), l5 = f1.y - hi_part(f1.y);
    const float l6 = f1.z - hi_part(f1.z), l7 = f1.w - hi_part(f1.w);
    ul.x = pack_hi(l0, l1);
    ul.y = pack_hi(l2, l3);
    ul.z = pack_hi(l4, l5);
    ul.w = pack_hi(l6, l7);
}

// Stage one wave's 16 vocab rows (19200 B) of tile `tile` into its part of dst.
__device__ __forceinline__ void stage16(const float* __restrict__ w_emb,
                                        int tile, int w, int lane, float* dst) {
    const float* gend = w_emb + (size_t)VV * EE - 4;
    const float* g = w_emb + ((size_t)tile * 64 + w * 16) * EE;
    float* d = dst + w * 4800;
#pragma unroll
    for (int i = 0; i < 19; ++i) {
        if (i < 18 || lane < 48) {             // 19200 B = 18.75 KB
            const int off = i * 256 + lane * 4;
            const float* src = g + off;
            if (src > gend) src = gend;        // tail-tile clamp, 16B-aligned
            gld_lds16(src, d + off);
        }
    }
}

// ===========================================================================
// PHASE 1 body (cent) and PHASE 2 body (row) as macros so the fused
// cooperative kernel and the two-kernel fallback share identical code.
// ROW_BODY is fully brace-scoped so its locals (rc*, rsc*) can't collide
// with CENT_BODY's when both expand in fused_kernel (round-6 compile fix).
// ===========================================================================
#define CENT_BODY(w_emb, a_emb, a_weight, cent)                                \
    const int t = threadIdx.x;                                                 \
    const int l = t & 63;                                                      \
    const int w = t >> 6;                                                      \
    const int m = l & 15;                                                      \
    const int kg = l >> 4;                                                     \
    {   /* aspect inv-norms + weights (8 lanes/aspect, threads 0..239) */      \
        const int a = t >> 3, j = t & 7;                                       \
        if (a < AA) {                                                          \
            const float4* a4 = (const float4*)a_emb + a * 75;                  \
            float n2a = 0.f;                                                   \
            for (int c = j; c < 75; c += 8) {                                  \
                const float4 x = a4[c];                                        \
                n2a += x.x * x.x + x.y * x.y + x.z * x.z + x.w * x.w;          \
            }                                                                  \
            n2a += __shfl_xor(n2a, 1);                                         \
            n2a += __shfl_xor(n2a, 2);                                         \
            n2a += __shfl_xor(n2a, 4);                                         \
            if (j == 0) {                                                      \
                s_scale[a] = 1.f / fmaxf(sqrtf(n2a), COS_EPS_F);               \
                s_aw[a] = a_weight[a];                                         \
            }                                                                  \
        }                                                                      \
        if (t == 30 || t == 31) { s_scale[t] = 0.f; s_aw[t] = 0.f; }           \
    }                                                                          \
    {   /* build B fragments (a_emb hi/lo) in pool head */                     \
        uint4* s_bfrag = s_pool;                                               \
        for (int ks = w; ks < 10; ks += 4) {                                   \
            const int kb = kg * 8 + 32 * ks;                                   \
            _Pragma("unroll")                                                  \
            for (int tt = 0; tt < 2; ++tt) {                                   \
                const int col = tt * 16 + m;                                   \
                float4 f0 = {0.f,0.f,0.f,0.f}, f1 = {0.f,0.f,0.f,0.f};         \
                if (col < AA) {                                                \
                    const float* ap = a_emb + col * EE;                        \
                    if (kb <= 296) f0 = *(const float4*)(ap + kb);             \
                    if (kb <= 292) f1 = *(const float4*)(ap + kb + 4);         \
                }                                                              \
                uint4 uh, ul;                                                  \
                cvt_hilo(f0, f1, uh, ul);                                      \
                s_bfrag[(ks * 4 + tt * 2 + 0) * 64 + l] = uh;                  \
                s_bfrag[(ks * 4 + tt * 2 + 1) * 64 + l] = ul;                  \
            }                                                                  \
        }                                                                      \
    }                                                                          \
    __syncthreads();                                                           \
    bf16x8 bfr[40];                                                            \
    _Pragma("unroll")                                                          \
    for (int q = 0; q < 40; ++q)                                               \
        bfr[q] = __builtin_bit_cast(bf16x8, s_pool[q * 64 + l]);               \
    __syncthreads();                                                           \
    float* buf0 = (float*)s_pool;                                              \
    float* buf1 = buf0 + 19200;                                                \
    const float sc0 = s_scale[m], aw0 = s_aw[m];                               \
    const float sc1 = s_scale[16 + m], aw1 = s_aw[16 + m];                     \
    const bool col1ok = (16 + m) < AA;                                         \
    int cur = 0;                                                               \
    int tile = blockIdx.x;                                                     \
    stage16(w_emb, tile, w, l, buf0);                                          \
    for (; tile < NTILES; tile += CGRID) {                                     \
        const int nxt = tile + CGRID;                                          \
        float* bufc = cur ? buf1 : buf0;                                       \
        if (nxt < NTILES) {                                                    \
            stage16(w_emb, nxt, w, l, cur ? buf0 : buf1);                      \
            asm volatile("s_waitcnt vmcnt(19)" ::: "memory");                  \
        } else {                                                               \
            asm volatile("s_waitcnt vmcnt(0)" ::: "memory");                   \
        }                                                                      \
        const float* arow = bufc + w * 4800 + m * 300;                         \
        f32x4 acc0 = {0.f, 0.f, 0.f, 0.f};                                     \
        f32x4 acc1 = {0.f, 0.f, 0.f, 0.f};                                     \
        float n2 = 0.f;                                                        \
        _Pragma("unroll")                                                      \
        for (int i = 0; i < 10; ++i) {                                         \
            const int kb = kg * 8 + 32 * i;                                    \
            float4 f0 = *(const float4*)(arow + kb);                           \
            float4 f1 = *(const float4*)(arow + kb + 4);                       \
            if (i == 9) {                                                      \
                const float4 z = {0.f, 0.f, 0.f, 0.f};                         \
                if (kg >= 2) f0 = z;                                           \
                if (kg >= 1) f1 = z;                                           \
            }                                                                  \
            n2 = fmaf(f0.x,f0.x, fmaf(f0.y,f0.y, fmaf(f0.z,f0.z,               \
                 fmaf(f0.w,f0.w, n2))));                                       \
            n2 = fmaf(f1.x,f1.x, fmaf(f1.y,f1.y, fmaf(f1.z,f1.z,               \
                 fmaf(f1.w,f1.w, n2))));                                       \
            uint4 uh, ul;                                                      \
            cvt_hilo(f0, f1, uh, ul);                                          \
            const bf16x8 ah = __builtin_bit_cast(bf16x8, uh);                  \
            const bf16x8 al = __builtin_bit_cast(bf16x8, ul);                  \
            acc0 = MFMA16(ah, bfr[i * 4 + 0], acc0);                           \
            acc1 = MFMA16(ah, bfr[i * 4 + 2], acc1);                           \
            acc0 = MFMA16(ah, bfr[i * 4 + 1], acc0);                           \
            acc1 = MFMA16(ah, bfr[i * 4 + 3], acc1);                           \
            acc0 = MFMA16(al, bfr[i * 4 + 0], acc0);                           \
            acc1 = MFMA16(al, bfr[i * 4 + 2], acc1);                           \
        }                                                                      \
        n2 += __shfl_xor(n2, 16);                                              \
        n2 += __shfl_xor(n2, 32);                                              \
        const int vtile = tile * 64 + w * 16;                                  \
        float mx[4];                                                           \
        _Pragma("unroll")                                                      \
        for (int j = 0; j < 4; ++j) {                                          \
            const int r = kg * 4 + j;                                          \
            const float n2r = __int_as_float(                                  \
                __builtin_amdgcn_ds_bpermute(r << 2, __float_as_int(n2)));     \
            const float inv_x = 1.f / fmaxf(sqrtf(n2r), COS_EPS_F);            \
            float c0 = acc0[j] * sc0 * inv_x;                                  \
            float c1 = acc1[j] * sc1 * inv_x;                                  \
            if (fabsf(c0 - WORD_THRES) < RECHECK_DELTA) {                      \
                const float* wr = bufc + w * 4800 + r * 300;                   \
                const float* ar = a_emb + m * EE;                              \
                float d = 0.f;                                                 \
                for (int k = 0; k < EE; ++k) d = fmaf(wr[k], ar[k], d);        \
                c0 = d * sc0 * inv_x;                                          \
            }                                                                  \
            if (col1ok && fabsf(c1 - WORD_THRES) < RECHECK_DELTA) {            \
                const float* wr = bufc + w * 4800 + r * 300;                   \
                const float* ar = a_emb + (16 + m) * EE;                       \
                float d = 0.f;                                                 \
                for (int k = 0; k < EE; ++k) d = fmaf(wr[k], ar[k], d);        \
                c1 = d * sc1 * inv_x;                                          \
            }                                                                  \
            float mj = fmaxf((c0 > WORD_THRES) ? c0 * aw0 : 0.f,               \
                             (c1 > WORD_THRES) ? c1 * aw1 : 0.f);              \
            mj = fmaxf(mj, __shfl_xor(mj, 1));                                 \
            mj = fmaxf(mj, __shfl_xor(mj, 2));                                 \
            mj = fmaxf(mj, __shfl_xor(mj, 4));                                 \
            mj = fmaxf(mj, __shfl_xor(mj, 8));                                 \
            mx[j] = mj;                                                        \
        }                                                                      \
        if (m == 0 && vtile < VV) {                                            \
            const float4 o = {mx[0], mx[1], mx[2], mx[3]};                     \
            *(float4*)(cent + vtile + kg * 4) = o;                             \
        }                                                                      \
        cur ^= 1;                                                              \
    }

// Row phase: wave `w` of the block handles batch row `brow`; lane owns 4
// contiguous positions (ids preloaded in id4). Entirely brace-scoped.
#define ROW_BODY(w_emb, cent, out, brow, id4, lane, w, s_id, s_w, s_n)         \
  {                                                                            \
    if (lane == 0) s_n[w] = 0;                                                 \
    const float rc0 = cent[id4.x];                                             \
    const float rc1 = cent[id4.y];                                             \
    const float rc2 = cent[id4.z];                                             \
    const float rc3 = cent[id4.w];                                             \
    const float rsc0 = (rc0 > 0.f) ? rc0 : NEG_INF_F;                          \
    const float rsc1 = (rc1 > 0.f) ? rc1 : NEG_INF_F;                          \
    const float rsc2 = (rc2 > 0.f) ? rc2 : NEG_INF_F;                          \
    const float rsc3 = (rc3 > 0.f) ? rc3 : NEG_INF_F;                          \
    float s1 = rc0 + rc1 + rc2 + rc3;                                          \
    float s2 = (id4.x != 0 ? 1.f : 0.f) + (id4.y != 0 ? 1.f : 0.f) +           \
               (id4.z != 0 ? 1.f : 0.f) + (id4.w != 0 ? 1.f : 0.f);            \
    float s3 = fmaxf(fmaxf(rsc0, rsc1), fmaxf(rsc2, rsc3));                    \
    _Pragma("unroll")                                                          \
    for (int o = 1; o < 64; o <<= 1) {                                         \
        s1 += __shfl_xor(s1, o);                                               \
        s2 += __shfl_xor(s2, o);                                               \
        s3 = fmaxf(s3, __shfl_xor(s3, o));                                     \
    }                                                                          \
    const float mxv = s3;                                                      \
    const float p0 = expf(rsc0 - mxv);                                         \
    const float p1 = expf(rsc1 - mxv);                                         \
    const float p2 = expf(rsc2 - mxv);                                         \
    const float p3 = expf(rsc3 - mxv);                                         \
    float s4 = p0 + p1 + p2 + p3;                                              \
    _Pragma("unroll")                                                          \
    for (int o = 1; o < 64; o <<= 1) s4 += __shfl_xor(s4, o);                  \
    const float rinv = 1.f / s4;                                               \
    const float4 av = {p0 * rinv, p1 * rinv, p2 * rinv, p3 * rinv};            \
    *(float4*)(out + BB * EE + brow * LL + lane * 4) = av;                     \
    const float cs = s1 / (s2 + 1e-5f);                                        \
    const float gate = (cs > 1e-4f) ? 1.f : 0.f;                               \
    if (lane == 0) out[BB * EE + BB * LL + brow] = cs;                         \
    if (rsc0 > -1e8f) { const int i = atomicAdd(&s_n[w], 1);                   \
        s_id[w * LL + i] = id4.x; s_w[w * LL + i] = av.x; }                    \
    if (rsc1 > -1e8f) { const int i = atomicAdd(&s_n[w], 1);                   \
        s_id[w * LL + i] = id4.y; s_w[w * LL + i] = av.y; }                    \
    if (rsc2 > -1e8f) { const int i = atomicAdd(&s_n[w], 1);                   \
        s_id[w * LL + i] = id4.z; s_w[w * LL + i] = av.z; }                    \
    if (rsc3 > -1e8f) { const int i = atomicAdd(&s_n[w], 1);                   \
        s_id[w * LL + i] = id4.w; s_w[w * LL + i] = av.w; }                    \
    __syncthreads();                                                           \
    const int n = s_n[w];                                                      \
    float4 accA = {0.f, 0.f, 0.f, 0.f};                                        \
    float4 accB = {0.f, 0.f, 0.f, 0.f};                                        \
    for (int i = 0; i < n; ++i) {                                              \
        const float wgt = s_w[w * LL + i];                                     \
        const float4* rp = (const float4*)(w_emb + (size_t)s_id[w*LL+i] * EE); \
        const float4 ra = rp[lane];                                            \
        accA.x += wgt * ra.x; accA.y += wgt * ra.y;                            \
        accA.z += wgt * ra.z; accA.w += wgt * ra.w;                            \
        if (lane < 11) {                                                       \
            const float4 rb = rp[64 + lane];                                   \
            accB.x += wgt * rb.x; accB.y += wgt * rb.y;                        \
            accB.z += wgt * rb.z; accB.w += wgt * rb.w;                        \
        }                                                                      \
    }                                                                          \
    accA.x *= gate; accA.y *= gate; accA.z *= gate; accA.w *= gate;            \
    *(float4*)(out + brow * EE + 4 * lane) = accA;                             \
    if (lane < 11) {                                                           \
        accB.x *= gate; accB.y *= gate; accB.z *= gate; accB.w *= gate;        \
        *(float4*)(out + brow * EE + 256 + 4 * lane) = accB;                   \
    }                                                                          \
  }

// ---------------------------------------------------------------------------
// Fused cooperative kernel: phase 1 (cent, persistent 256 blocks, dbuf DMA,
// B-in-VGPR) -> grid sync -> phase 2 (wave-per-batch-row). Removes the second
// launch + inter-kernel gap; phase-2's input ids are preloaded into registers
// before the grid barrier so their latency hides under the sync wait.
// ---------------------------------------------------------------------------
__global__ void __launch_bounds__(256, 1) fused_kernel(
    const int* __restrict__ inputs,
    const float* __restrict__ w_emb,
    const float* __restrict__ a_emb,
    const float* __restrict__ a_weight,
    float* __restrict__ cent,
    float* __restrict__ out)
{
    __shared__ uint4 s_pool[9600];       // 153600 B: two 76800 B A-buffers
    __shared__ float s_scale[32];
    __shared__ float s_aw[32];

    CENT_BODY(w_emb, a_emb, a_weight, cent)

    // preload phase-2 ids (independent of phase 1) before the grid barrier
    const int brow = blockIdx.x * 4 + w;
    const int4 id4 = *(const int4*)(inputs + brow * LL + l * 4);

    __threadfence();
    cg::this_grid().sync();
    __syncthreads();

    // phase-2 LDS carved from the (now dead) phase-1 pool
    int* p2_id = (int*)s_pool;             // [4][256]
    float* p2_w = (float*)s_pool + 1024;   // [4][256]
    int* p2_n = (int*)s_pool + 2048;       // [4]

    ROW_BODY(w_emb, cent, out, brow, id4, l, w, p2_id, p2_w, p2_n)
}

// ---------------------------------------------------------------------------
// Fallback pair (identical bodies) in case cooperative launch is unavailable.
// ---------------------------------------------------------------------------
__global__ void __launch_bounds__(256, 1) cent_kernel(
    const float* __restrict__ w_emb,
    const float* __restrict__ a_emb,
    const float* __restrict__ a_weight,
    float* __restrict__ cent)
{
    __shared__ uint4 s_pool[9600];
    __shared__ float s_scale[32];
    __shared__ float s_aw[32];
    CENT_BODY(w_emb, a_emb, a_weight, cent)
}

__global__ void __launch_bounds__(256) row_kernel(
    const int* __restrict__ inputs,
    const float* __restrict__ w_emb,
    const float* __restrict__ cent,
    float* __restrict__ out)
{
    __shared__ int s_id[4 * LL];
    __shared__ float s_w[4 * LL];
    __shared__ int s_n[4];
    const int w = threadIdx.x >> 6;
    const int lane = threadIdx.x & 63;
    const int brow = blockIdx.x * 4 + w;
    const int4 id4 = *(const int4*)(inputs + brow * LL + lane * 4);
    ROW_BODY(w_emb, cent, out, brow, id4, lane, w, s_id, s_w, s_n)
}

// ---------------------------------------------------------------------------
extern "C" void kernel_launch(void* const* d_in, const int* in_sizes, int n_in,
                              void* d_out, int out_size, void* d_ws, size_t ws_size,
                              hipStream_t stream) {
    const int* inputs = (const int*)d_in[0];
    const float* w_emb = (const float*)d_in[1];
    const float* a_emb = (const float*)d_in[2];
    const float* a_weight = (const float*)d_in[3];
    float* out = (float*)d_out;
    float* cent = (float*)d_ws;  // 50000 floats = 200 KB scratch

    static int coop = -1;
    if (coop < 0) {
        int dev = 0;
        (void)hipGetDevice(&dev);
        if (hipDeviceGetAttribute(&coop, hipDeviceAttributeCooperativeLaunch,
                                  dev) != hipSuccess)
            coop = 0;
    }

    bool launched = false;
    if (coop) {
        void* args[] = {(void*)&inputs, (void*)&w_emb, (void*)&a_emb,
                        (void*)&a_weight, (void*)&cent, (void*)&out};
        if (hipLaunchCooperativeKernel((const void*)fused_kernel, dim3(CGRID),
                                       dim3(256), args, 0, stream) == hipSuccess)
            launched = true;
    }
    if (!launched) {
        cent_kernel<<<CGRID, 256, 0, stream>>>(w_emb, a_emb, a_weight, cent);
        row_kernel<<<BB / 4, 256, 0, stream>>>(inputs, w_emb, cent, out);
    }
}

// Round 8
// 112.244 us; speedup vs baseline: 1.6374x; 1.6374x over previous
//
#include <hip/hip_runtime.h>
#include <math.h>

#define BB 1024
#define LL 256
#define VV 50000
#define EE 300
#define AA 30
#define WORD_THRES 0.2f
#define COS_EPS_F 1e-8f
#define NEG_INF_F -1e9f
#define RECHECK_DELTA 2e-4f

typedef __attribute__((ext_vector_type(8))) short bf16x8;
typedef __attribute__((ext_vector_type(4))) float f32x4;

#define MFMA16(a, b, c) __builtin_amdgcn_mfma_f32_16x16x32_bf16((a), (b), (c), 0, 0, 0)

// fp32 -> bf16 truncation split: x = hi + lo with |x - hi - lo| <~ 2^-17 |x|.
__device__ __forceinline__ unsigned pack_hi(float a, float b) {
    return (__float_as_uint(a) >> 16) | (__float_as_uint(b) & 0xFFFF0000u);
}
__device__ __forceinline__ float hi_part(float a) {
    return __uint_as_float(__float_as_uint(a) & 0xFFFF0000u);
}
__device__ __forceinline__ void cvt_hilo(const float4 f0, const float4 f1,
                                         uint4& uh, uint4& ul) {
    uh.x = pack_hi(f0.x, f0.y);
    uh.y = pack_hi(f0.z, f0.w);
    uh.z = pack_hi(f1.x, f1.y);
    uh.w = pack_hi(f1.z, f1.w);
    const float l0 = f0.x - hi_part(f0.x), l1 = f0.y - hi_part(f0.y);
    const float l2 = f0.z - hi_part(f0.z), l3 = f0.w - hi_part(f0.w);
    const float l4 = f1.x - hi_part(f1.x), l5 = f1.y - hi_part(f1.y);
    const float l6 = f1.z - hi_part(f1.z), l7 = f1.w - hi_part(f1.w);
    ul.x = pack_hi(l0, l1);
    ul.y = pack_hi(l2, l3);
    ul.z = pack_hi(l4, l5);
    ul.w = pack_hi(l6, l7);
}

// clamped pair load: safe addresses for the zero-padded tail k-step
__device__ __forceinline__ void ld_pair(const float* __restrict__ rowp, int kb,
                                        float4& a, float4& b) {
    const int k0 = (kb > 296) ? 296 : kb;
    const int k1 = (kb + 4 > 296) ? 296 : (kb + 4);
    a = *(const float4*)(rowp + k0);
    b = *(const float4*)(rowp + k1);
}

// ---------------------------------------------------------------------------
// Kernel 1 (MFMA): cent[v] = max_a ((cos(a_emb[a], w_emb[v]) > thres ? cos : 0) * w[a])
// [V,300]x[300,30] GEMM via mfma_f32_16x16x32_bf16 with hi/lo bf16 split.
// SESSION NOTE (rounds 0-7): cent's ~43 us duration is invariant under
// VALU/MFMA formulation, reg/DMA staging, 8-24% occupancy, 30-65 MB moved,
// and cache-cold/warm (R7: 87 us fused with 2.5 MB HBM traffic) -> the floor
// is environmental (post-fill clock ramp / harness window), not kernel-side.
// This is the round-3 configuration, the session-best total (111.0 us).
// ---------------------------------------------------------------------------
__global__ void __launch_bounds__(256) cent_kernel(
    const float* __restrict__ w_emb,     // [V, E]
    const float* __restrict__ a_emb,     // [A, E]
    const float* __restrict__ a_weight,  // [A]
    float* __restrict__ cent)            // [V]
{
    __shared__ uint4 s_bfrag[40 * 64];   // [ks*4 + tt*2 + (hi/lo)][lane], 40960 B
    __shared__ float s_scale[32];
    __shared__ float s_aw[32];

    const int t = threadIdx.x;
    const int l = t & 63;
    const int w = t >> 6;
    const int m = l & 15;        // row within tile / aspect lane id
    const int kg = l >> 4;       // k-chunk selector (8 elements each)

    // ---- aspect inv-norms + weights (8 lanes per aspect, threads 0..239) ----
    {
        const int a = t >> 3, j = t & 7;
        if (a < AA) {
            const float4* a4 = (const float4*)a_emb + a * 75;
            float n2a = 0.f;
            for (int c = j; c < 75; c += 8) {
                const float4 x = a4[c];
                n2a += x.x * x.x + x.y * x.y + x.z * x.z + x.w * x.w;
            }
            n2a += __shfl_xor(n2a, 1);
            n2a += __shfl_xor(n2a, 2);
            n2a += __shfl_xor(n2a, 4);
            if (j == 0) {
                s_scale[a] = 1.f / fmaxf(sqrtf(n2a), COS_EPS_F);
                s_aw[a] = a_weight[a];
            }
        }
        if (t == 30 || t == 31) { s_scale[t] = 0.f; s_aw[t] = 0.f; }  // pad cols
    }

    // ---- build B fragments (a_emb hi/lo), waves split the 10 k-steps ----
    for (int ks = w; ks < 10; ks += 4) {
        const int kb = kg * 8 + 32 * ks;
#pragma unroll
        for (int tt = 0; tt < 2; ++tt) {
            const int col = tt * 16 + m;         // aspect index (pad >= 30)
            float4 f0 = {0.f, 0.f, 0.f, 0.f}, f1 = {0.f, 0.f, 0.f, 0.f};
            if (col < AA) {
                const float* ap = a_emb + col * EE;
                if (kb <= 296) f0 = *(const float4*)(ap + kb);
                if (kb <= 292) f1 = *(const float4*)(ap + kb + 4);
            }
            uint4 uh, ul;
            cvt_hilo(f0, f1, uh, ul);
            s_bfrag[(ks * 4 + tt * 2 + 0) * 64 + l] = uh;
            s_bfrag[(ks * 4 + tt * 2 + 1) * 64 + l] = ul;
        }
    }
    __syncthreads();

    // ---- main loop: one 16-row M-tile per wave, 5-deep load ring ----
    const int vbase = blockIdx.x * 64 + w * 16;
    const int v = vbase + m;
    const float* __restrict__ rowp = w_emb + (size_t)((v < VV) ? v : 0) * EE;

    f32x4 acc0 = {0.f, 0.f, 0.f, 0.f};
    f32x4 acc1 = {0.f, 0.f, 0.f, 0.f};
    float n2 = 0.f;
    const uint4* __restrict__ bp0 = s_bfrag + l;

    float4 pa[5], pb[5];
#pragma unroll
    for (int i = 0; i < 5; ++i)
        ld_pair(rowp, kg * 8 + 32 * i, pa[i], pb[i]);

#pragma unroll
    for (int i = 0; i < 10; ++i) {
        const int s = i % 5;                       // static under full unroll
        float4 f0 = pa[s], f1 = pb[s];
        if (i < 5)                                 // prefetch step i+5
            ld_pair(rowp, kg * 8 + 32 * (i + 5), pa[s], pb[s]);
        if (i == 9) {                              // zero-padded tail lanes
            const float4 z = {0.f, 0.f, 0.f, 0.f};
            if (kg >= 2) f0 = z;                   // kb=304/312: out of row
            if (kg >= 1) f1 = z;                   // kb+4>=300
        }
        n2 = fmaf(f0.x, f0.x, fmaf(f0.y, f0.y, fmaf(f0.z, f0.z, fmaf(f0.w, f0.w, n2))));
        n2 = fmaf(f1.x, f1.x, fmaf(f1.y, f1.y, fmaf(f1.z, f1.z, fmaf(f1.w, f1.w, n2))));
        uint4 uh, ul;
        cvt_hilo(f0, f1, uh, ul);
        const bf16x8 ah = __builtin_bit_cast(bf16x8, uh);
        const bf16x8 al = __builtin_bit_cast(bf16x8, ul);
        const uint4* bp = bp0 + i * 256;
        const bf16x8 bh0 = __builtin_bit_cast(bf16x8, bp[0]);
        const bf16x8 bl0 = __builtin_bit_cast(bf16x8, bp[64]);
        const bf16x8 bh1 = __builtin_bit_cast(bf16x8, bp[128]);
        const bf16x8 bl1 = __builtin_bit_cast(bf16x8, bp[192]);
        acc0 = MFMA16(ah, bh0, acc0);
        acc1 = MFMA16(ah, bh1, acc1);
        acc0 = MFMA16(ah, bl0, acc0);
        acc1 = MFMA16(ah, bl1, acc1);
        acc0 = MFMA16(al, bh0, acc0);
        acc1 = MFMA16(al, bh1, acc1);
    }

    // ---- epilogue ----
    n2 += __shfl_xor(n2, 16);
    n2 += __shfl_xor(n2, 32);
    // C/D layout: lane l holds D[rows kg*4+j][col m (+16 for acc1)]

    const float sc0 = s_scale[m], aw0 = s_aw[m];
    const float sc1 = s_scale[16 + m], aw1 = s_aw[16 + m];
    const bool col1ok = (16 + m) < AA;
    float mx[4];
#pragma unroll
    for (int j = 0; j < 4; ++j) {
        const int r = kg * 4 + j;                 // row within tile
        const float n2r = __int_as_float(
            __builtin_amdgcn_ds_bpermute(r << 2, __float_as_int(n2)));
        const float inv_x = 1.f / fmaxf(sqrtf(n2r), COS_EPS_F);
        float c0 = acc0[j] * sc0 * inv_x;
        float c1 = acc1[j] * sc1 * inv_x;
        // exact fp32 recheck for near-threshold cos values (rare: ~10 globally)
        if (fabsf(c0 - WORD_THRES) < RECHECK_DELTA) {
            const int rr = vbase + r;
            const float* wr = w_emb + (size_t)((rr < VV) ? rr : 0) * EE;
            const float* ar = a_emb + m * EE;
            float d = 0.f;
            for (int k = 0; k < EE; ++k) d = fmaf(wr[k], ar[k], d);
            c0 = d * sc0 * inv_x;
        }
        if (col1ok && fabsf(c1 - WORD_THRES) < RECHECK_DELTA) {
            const int rr = vbase + r;
            const float* wr = w_emb + (size_t)((rr < VV) ? rr : 0) * EE;
            const float* ar = a_emb + (16 + m) * EE;
            float d = 0.f;
            for (int k = 0; k < EE; ++k) d = fmaf(wr[k], ar[k], d);
            c1 = d * sc1 * inv_x;
        }
        float mj = fmaxf((c0 > WORD_THRES) ? c0 * aw0 : 0.f,
                         (c1 > WORD_THRES) ? c1 * aw1 : 0.f);
        mj = fmaxf(mj, __shfl_xor(mj, 1));
        mj = fmaxf(mj, __shfl_xor(mj, 2));
        mj = fmaxf(mj, __shfl_xor(mj, 4));
        mj = fmaxf(mj, __shfl_xor(mj, 8));
        mx[j] = mj;
    }
    if (m == 0 && vbase < VV) {
        const float4 o = {mx[0], mx[1], mx[2], mx[3]};
        *(float4*)(cent + vbase + kg * 4) = o;   // rows kg*4..kg*4+3
    }
}

// ---------------------------------------------------------------------------
// Kernel 2: ONE WAVE per batch row (4 rows/block, 256 blocks). Lane owns 4
// contiguous positions -> int4 input load, 4 cent gathers, all reductions as
// one 6-level shuffle butterfly, coalesced float4 attention write. One barrier.
// Sparse z over the ~2 active positions per row.
// ---------------------------------------------------------------------------
__global__ void __launch_bounds__(256) row_kernel(
    const int* __restrict__ inputs,   // [B, L]
    const float* __restrict__ w_emb,  // [V, E]
    const float* __restrict__ cent,   // [V]
    float* __restrict__ out)          // enc_out [B,E] | a [B,L] | cs [B]
{
    const int w = threadIdx.x >> 6;
    const int lane = threadIdx.x & 63;
    const int b = blockIdx.x * 4 + w;           // wave-per-row

    __shared__ int s_id[4][LL];
    __shared__ float s_w[4][LL];
    __shared__ int s_n[4];

    if (lane == 0) s_n[w] = 0;

    const int4 id4 = *(const int4*)(inputs + b * LL + lane * 4);
    const float c0 = cent[id4.x];
    const float c1 = cent[id4.y];
    const float c2 = cent[id4.z];
    const float c3 = cent[id4.w];
    const float sc0 = (c0 > 0.f) ? c0 : NEG_INF_F;
    const float sc1 = (c1 > 0.f) ? c1 : NEG_INF_F;
    const float sc2 = (c2 > 0.f) ? c2 : NEG_INF_F;
    const float sc3 = (c3 > 0.f) ? c3 : NEG_INF_F;

    float s1 = c0 + c1 + c2 + c3;                             // sum cent
    float s2 = (id4.x != 0 ? 1.f : 0.f) + (id4.y != 0 ? 1.f : 0.f) +
               (id4.z != 0 ? 1.f : 0.f) + (id4.w != 0 ? 1.f : 0.f);
    float s3 = fmaxf(fmaxf(sc0, sc1), fmaxf(sc2, sc3));       // max score
#pragma unroll
    for (int o = 1; o < 64; o <<= 1) {
        s1 += __shfl_xor(s1, o);
        s2 += __shfl_xor(s2, o);
        s3 = fmaxf(s3, __shfl_xor(s3, o));
    }
    const float mx = s3;

    const float p0 = expf(sc0 - mx);
    const float p1 = expf(sc1 - mx);
    const float p2 = expf(sc2 - mx);
    const float p3 = expf(sc3 - mx);
    float s4 = p0 + p1 + p2 + p3;
#pragma unroll
    for (int o = 1; o < 64; o <<= 1) s4 += __shfl_xor(s4, o);

    const float rinv = 1.f / s4;
    const float4 av = {p0 * rinv, p1 * rinv, p2 * rinv, p3 * rinv};
    *(float4*)(out + BB * EE + b * LL + lane * 4) = av;       // attention

    const float cs = s1 / (s2 + 1e-5f);
    const float gate = (cs > 1e-4f) ? 1.f : 0.f;
    if (lane == 0) out[BB * EE + BB * LL + b] = cs;

    // per-wave active list (score > -1e8 <=> cent > 0)
    if (sc0 > -1e8f) { const int i = atomicAdd(&s_n[w], 1); s_id[w][i] = id4.x; s_w[w][i] = av.x; }
    if (sc1 > -1e8f) { const int i = atomicAdd(&s_n[w], 1); s_id[w][i] = id4.y; s_w[w][i] = av.y; }
    if (sc2 > -1e8f) { const int i = atomicAdd(&s_n[w], 1); s_id[w][i] = id4.z; s_w[w][i] = av.z; }
    if (sc3 > -1e8f) { const int i = atomicAdd(&s_n[w], 1); s_id[w][i] = id4.w; s_w[w][i] = av.w; }
    __syncthreads();                              // order LDS list vs reads
    const int n = s_n[w];

    // z over active entries; lane owns float4 col lane (+ col 64+lane if <11)
    float4 accA = {0.f, 0.f, 0.f, 0.f};
    float4 accB = {0.f, 0.f, 0.f, 0.f};
    for (int i = 0; i < n; ++i) {
        const float wgt = s_w[w][i];
        const float4* rp = (const float4*)(w_emb + (size_t)s_id[w][i] * EE);
        const float4 ra = rp[lane];
        accA.x += wgt * ra.x; accA.y += wgt * ra.y;
        accA.z += wgt * ra.z; accA.w += wgt * ra.w;
        if (lane < 11) {
            const float4 rb = rp[64 + lane];
            accB.x += wgt * rb.x; accB.y += wgt * rb.y;
            accB.z += wgt * rb.z; accB.w += wgt * rb.w;
        }
    }
    accA.x *= gate; accA.y *= gate; accA.z *= gate; accA.w *= gate;
    *(float4*)(out + b * EE + 4 * lane) = accA;
    if (lane < 11) {
        accB.x *= gate; accB.y *= gate; accB.z *= gate; accB.w *= gate;
        *(float4*)(out + b * EE + 256 + 4 * lane) = accB;
    }
}

// ---------------------------------------------------------------------------
extern "C" void kernel_launch(void* const* d_in, const int* in_sizes, int n_in,
                              void* d_out, int out_size, void* d_ws, size_t ws_size,
                              hipStream_t stream) {
    const int* inputs = (const int*)d_in[0];
    const float* w_emb = (const float*)d_in[1];
    const float* a_emb = (const float*)d_in[2];
    const float* a_weight = (const float*)d_in[3];
    float* out = (float*)d_out;
    float* cent = (float*)d_ws;  // 50000 floats = 200 KB scratch

    cent_kernel<<<(VV + 63) / 64, 256, 0, stream>>>(w_emb, a_emb, a_weight, cent);
    row_kernel<<<BB / 4, 256, 0, stream>>>(inputs, w_emb, cent, out);
}